// Round 18
// baseline (103.494 us; speedup 1.0000x reference)
//
#include <hip/hip_runtime.h>
#include <hip/hip_bf16.h>
#include <cstdint>
#include <cstddef>

typedef __attribute__((ext_vector_type(4))) float  f32x4;
typedef __attribute__((ext_vector_type(8))) short  short8;

typedef __attribute__((address_space(3))) uint32_t as3_u32;
typedef __attribute__((address_space(1))) uint32_t as1_u32;

// bf16 RNE via hardware cvt (compiler fuses pairs into v_cvt_pk_bf16_f32)
__device__ __forceinline__ short f2bf(float f) {
  __hip_bfloat16 h = __float2bfloat16(f);
  return *reinterpret_cast<short*>(&h);
}
__device__ __forceinline__ float sigmoidf(float x) {
  return 1.0f / (1.0f + __expf(-x));
}

// ---------------- pool: g[b,c] = mean_s x[b,c,s] -> bf16 --------------------
__global__ __launch_bounds__(256) void pool_kernel(const float* __restrict__ x,
                                                   short* __restrict__ g) {
  __shared__ float sums[784];
  const int tid = threadIdx.x;
  const f32x4* base = (const f32x4*)(x + (size_t)blockIdx.x * (16 * 196));
#pragma unroll
  for (int it = 0; it < 4; ++it) {
    int i = it * 256 + tid;
    if (it < 3 || tid < 16) {
      f32x4 v = base[i];
      sums[i] = v[0] + v[1] + v[2] + v[3];
    }
  }
  __syncthreads();
  if (tid < 16) {
    float s = 0.f;
#pragma unroll
    for (int j = 0; j < 49; ++j) s += sums[tid * 49 + j];
    g[blockIdx.x * 16 + tid] = f2bf(s * (1.0f / 196.0f));
  }
}

// --------- GEMM1 (R11-proven): 1-deep reg prefetch, 16-wave K-split ---------
template<int N, int K, int WAVES, bool OUT_BF16>
__device__ __forceinline__ void gemm_body(const short* __restrict__ A,
                                          const float* __restrict__ B,
                                          const float* __restrict__ bias,
                                          void* __restrict__ outp,
                                          float* __restrict__ red) {
  constexpr int KW = K / WAVES;
  constexpr int NK = KW / 32;
  constexpr int NT = WAVES * 64;
  const int n0  = blockIdx.x * 16;
  const int tid = threadIdx.x;
  const int l   = tid & 63;
  const int wv  = tid >> 6;
  const int kw0 = wv * KW;

  const int ko = (l >> 4) * 8;
  const float* Bp = B + (size_t)(n0 + (l & 15)) * K + kw0 + ko;
  const short* Ap = A + (size_t)(l & 15) * K + kw0 + ko;

  f32x4 acc0 = {}, acc1 = {}, acc2 = {}, acc3 = {};

  f32x4 bc0 = *(const f32x4*)(Bp);
  f32x4 bc1 = *(const f32x4*)(Bp + 4);
  short8 ac0 = *(const short8*)(Ap);
  short8 ac1 = *(const short8*)(Ap + 16 * K);
  short8 ac2 = *(const short8*)(Ap + 32 * K);
  short8 ac3 = *(const short8*)(Ap + 48 * K);

  for (int t = 0; t < NK; ++t) {
    f32x4 bn0 = {}, bn1 = {};
    short8 an0 = {}, an1 = {}, an2 = {}, an3 = {};
    if (t + 1 < NK) {
      const float* bp = Bp + (t + 1) * 32;
      const short* ap = Ap + (t + 1) * 32;
      bn0 = *(const f32x4*)(bp);
      bn1 = *(const f32x4*)(bp + 4);
      an0 = *(const short8*)(ap);
      an1 = *(const short8*)(ap + 16 * K);
      an2 = *(const short8*)(ap + 32 * K);
      an3 = *(const short8*)(ap + 48 * K);
    }
    short8 bb;
    bb[0] = f2bf(bc0[0]); bb[1] = f2bf(bc0[1]); bb[2] = f2bf(bc0[2]); bb[3] = f2bf(bc0[3]);
    bb[4] = f2bf(bc1[0]); bb[5] = f2bf(bc1[1]); bb[6] = f2bf(bc1[2]); bb[7] = f2bf(bc1[3]);
    acc0 = __builtin_amdgcn_mfma_f32_16x16x32_bf16(ac0, bb, acc0, 0, 0, 0);
    acc1 = __builtin_amdgcn_mfma_f32_16x16x32_bf16(ac1, bb, acc1, 0, 0, 0);
    acc2 = __builtin_amdgcn_mfma_f32_16x16x32_bf16(ac2, bb, acc2, 0, 0, 0);
    acc3 = __builtin_amdgcn_mfma_f32_16x16x32_bf16(ac3, bb, acc3, 0, 0, 0);
    bc0 = bn0; bc1 = bn1;
    ac0 = an0; ac1 = an1; ac2 = an2; ac3 = an3;
  }

  {
    float* rw = red + wv * 1024;
    const int mb = (l >> 4) << 2;
    const int nn = l & 15;
#pragma unroll
    for (int r = 0; r < 4; ++r) rw[(0  + mb + r) * 16 + nn] = acc0[r];
#pragma unroll
    for (int r = 0; r < 4; ++r) rw[(16 + mb + r) * 16 + nn] = acc1[r];
#pragma unroll
    for (int r = 0; r < 4; ++r) rw[(32 + mb + r) * 16 + nn] = acc2[r];
#pragma unroll
    for (int r = 0; r < 4; ++r) rw[(48 + mb + r) * 16 + nn] = acc3[r];
  }
  __syncthreads();

#pragma unroll
  for (int i = tid; i < 1024; i += NT) {
    float s = 0.f;
#pragma unroll
    for (int w = 0; w < WAVES; ++w) s += red[w * 1024 + i];
    int m  = i >> 4;
    int nn = i & 15;
    nn += n0;
    s = sigmoidf(s + bias[nn]);
    if constexpr (OUT_BF16) ((short*)outp)[(size_t)m * N + nn] = f2bf(s);
    else                    ((float*)outp)[(size_t)m * N + nn] = s;
  }
}

// GEMM1: 16 waves (1024 threads), 256 blocks -> 16 waves/CU
__global__ __launch_bounds__(1024, 4) void gemm1_kernel(const short* __restrict__ A,
                                                        const float* __restrict__ B,
                                                        const float* __restrict__ bias,
                                                        short* __restrict__ outp) {
  __shared__ float red[16 * 1024];
  gemm_body<4096, 2048, 16, true>(A, B, bias, outp, red);
}

// --------- GEMM2: contiguity-maximizing mega-chunk stage --------------------
// 512 blocks x 8 waves; n-tile = 16 w2-rows = CONTIGUOUS 256 KB of w2.
// K in 2 mega-chunks: stage 16 rows x 8 KB (128 KB LDS, single-buffered,
// 1 block/CU) -> 8 KB contiguous bursts per row (vs 1 KB before) to test the
// strided-short-burst HBM-efficiency hypothesis. 16 global_load_lds per
// thread back-to-back => hundreds of KB in flight per CU during stage.
// Only 2 vmcnt(0) drains total (amortized). Both-sides XOR swizzle (G21):
// LDS[row][d] = G[row][d ^ ((row&7)<<4)], row pitch 8192 B.
__global__ __launch_bounds__(512) void gemm2_kernel(const short* __restrict__ A,
                                                    const float* __restrict__ B,
                                                    const float* __restrict__ bias,
                                                    float* __restrict__ outp,
                                                    float* __restrict__ zbuf) {
  constexpr int N = 8192, K = 4096;
  __shared__ char ldsb[131072];         // 128 KB B-tile (reused as red[] after)
  const int tid = threadIdx.x;
  const int l   = tid & 63;
  const int wv  = tid >> 6;
  const int n0  = blockIdx.x * 16;

  // zero feat for einsum's atomics (512 blocks x 98 = 50176 floats)
  if (tid < 98) zbuf[blockIdx.x * 98 + tid] = 0.f;

  const char*  gB = (const char*)B + (size_t)n0 * (K * 4);   // 16 KB per row
  const short* Ap = A + (size_t)(l & 15) * K + ((l >> 4) << 3);

  f32x4 acc0 = {}, acc1 = {}, acc2 = {}, acc3 = {};

  const int row = l & 15;
  const int swz = (row & 7) << 4;
  const int rb  = row * 8192;
  const int dsw = tid * 16;             // this thread's dest byte (lane x 16)
  const int dstu = (tid & ~63) * 16;    // wave-uniform part of dest

#pragma unroll 1
  for (int ch = 0; ch < 2; ++ch) {
    __syncthreads();                    // prev chunk's LDS reads complete
    // stage: 16 rows x 8 KB contiguous, pre-swizzled source
#pragma unroll
    for (int j = 0; j < 16; ++j) {
      const char* src = gB + (size_t)j * (K * 4) + (size_t)ch * 8192
                           + (dsw ^ ((j & 7) << 4));
      char* dst = ldsb + j * 8192 + dstu;
      __builtin_amdgcn_global_load_lds((as1_u32*)src, (as3_u32*)dst, 16, 0, 0);
    }
    __syncthreads();                    // vmcnt(0) drain: tile visible

    // compute: wave wv covers k in [ch*2048 + wv*256, +256) = 8 k-steps,
    // A (L2-resident) 1-step-ahead prefetch
    const short* ap0 = Ap + ch * 2048 + wv * 256;
    short8 aC0 = *(const short8*)(ap0);
    short8 aC1 = *(const short8*)(ap0 + 16 * K);
    short8 aC2 = *(const short8*)(ap0 + 32 * K);
    short8 aC3 = *(const short8*)(ap0 + 48 * K);
#pragma unroll
    for (int t = 0; t < 8; ++t) {
      short8 aN0 = {}, aN1 = {}, aN2 = {}, aN3 = {};
      if (t + 1 < 8) {
        const short* ap = ap0 + (t + 1) * 32;
        aN0 = *(const short8*)(ap);
        aN1 = *(const short8*)(ap + 16 * K);
        aN2 = *(const short8*)(ap + 32 * K);
        aN3 = *(const short8*)(ap + 48 * K);
      }
      const int koff = (wv << 10) + (t << 7) + ((l >> 4) << 5);
      f32x4 b0 = *(const f32x4*)(ldsb + rb + ((koff)      ^ swz));
      f32x4 b1 = *(const f32x4*)(ldsb + rb + ((koff + 16) ^ swz));
      short8 bb;
      bb[0] = f2bf(b0[0]); bb[1] = f2bf(b0[1]); bb[2] = f2bf(b0[2]); bb[3] = f2bf(b0[3]);
      bb[4] = f2bf(b1[0]); bb[5] = f2bf(b1[1]); bb[6] = f2bf(b1[2]); bb[7] = f2bf(b1[3]);
      acc0 = __builtin_amdgcn_mfma_f32_16x16x32_bf16(aC0, bb, acc0, 0, 0, 0);
      acc1 = __builtin_amdgcn_mfma_f32_16x16x32_bf16(aC1, bb, acc1, 0, 0, 0);
      acc2 = __builtin_amdgcn_mfma_f32_16x16x32_bf16(aC2, bb, acc2, 0, 0, 0);
      acc3 = __builtin_amdgcn_mfma_f32_16x16x32_bf16(aC3, bb, acc3, 0, 0, 0);
      aC0 = aN0; aC1 = aN1; aC2 = aN2; aC3 = aN3;
    }
  }

  // epilogue: reuse LDS as red[8][1024]
  __syncthreads();
  float* red = (float*)ldsb;
  {
    float* rw = red + wv * 1024;
    const int mb = (l >> 4) << 2;
    const int nn = l & 15;
#pragma unroll
    for (int r = 0; r < 4; ++r) rw[(0  + mb + r) * 16 + nn] = acc0[r];
#pragma unroll
    for (int r = 0; r < 4; ++r) rw[(16 + mb + r) * 16 + nn] = acc1[r];
#pragma unroll
    for (int r = 0; r < 4; ++r) rw[(32 + mb + r) * 16 + nn] = acc2[r];
#pragma unroll
    for (int r = 0; r < 4; ++r) rw[(48 + mb + r) * 16 + nn] = acc3[r];
  }
  __syncthreads();
#pragma unroll
  for (int i = tid; i < 1024; i += 512) {
    float s = 0.f;
#pragma unroll
    for (int w = 0; w < 8; ++w) s += red[w * 1024 + i];
    int m  = i >> 4;
    int nn = n0 + (i & 15);
    outp[(size_t)m * N + nn] = sigmoidf(s + bias[nn]);
  }
}

// --------- einsum: feat[b,p,s] += (1/C) sum_{c in chunk} w[b,p,c] x[b,c,s] --
__global__ __launch_bounds__(256) void einsum_kernel(const float* __restrict__ x,
                                                     const float* __restrict__ wg,
                                                     float* __restrict__ feat) {
  const int b   = blockIdx.x >> 4;
  const int cc  = blockIdx.x & 15;
  const int tid = threadIdx.x;
  if (tid >= 196) return;
  const float* wp = wg + (size_t)b * 8192 + cc * 128;
  const float* xp = x + (size_t)b * 2048 * 196 + (size_t)cc * 128 * 196 + tid;
  float a0 = 0.f, a1 = 0.f, a2 = 0.f, a3 = 0.f;
#pragma unroll 8
  for (int c = 0; c < 128; ++c) {
    float xv = xp[(size_t)c * 196];
    a0 = __builtin_fmaf(wp[c],        xv, a0);
    a1 = __builtin_fmaf(wp[2048 + c], xv, a1);
    a2 = __builtin_fmaf(wp[4096 + c], xv, a2);
    a3 = __builtin_fmaf(wp[6144 + c], xv, a3);
  }
  const float invC = 1.0f / 2048.0f;
  atomicAdd(feat + (b * 4 + 0) * 196 + tid, a0 * invC);
  atomicAdd(feat + (b * 4 + 1) * 196 + tid, a1 * invC);
  atomicAdd(feat + (b * 4 + 2) * 196 + tid, a2 * invC);
  atomicAdd(feat + (b * 4 + 3) * 196 + tid, a3 * invC);
}

extern "C" void kernel_launch(void* const* d_in, const int* in_sizes, int n_in,
                              void* d_out, int out_size, void* d_ws, size_t ws_size,
                              hipStream_t stream) {
  const float* x  = (const float*)d_in[0];   // [64,2048,14,14]
  const float* w1 = (const float*)d_in[1];   // [4096,2048]
  const float* b1 = (const float*)d_in[2];   // [4096]
  const float* w2 = (const float*)d_in[3];   // [8192,4096]
  const float* b2 = (const float*)d_in[4];   // [8192]
  float* out = (float*)d_out;

  short* g_bf = (short*)d_ws;                // 64*2048 bf16 (256 KB)
  short* h_bf = g_bf + 64 * 2048;            // 64*4096 bf16 (512 KB)

  float* wout = out;                         // [64, 8192] == [B,P,C] flat
  float* feat = out + 524288;                // [64, 4, 196]

  // 1) pool -> g (bf16): 8192 blocks x 16 rows
  pool_kernel<<<(64 * 2048) / 16, 256, 0, stream>>>(x, g_bf);

  // 2) GEMM1: h = sigmoid(g @ w1^T + b1), bf16 out (256 blocks x 16 waves)
  gemm1_kernel<<<4096 / 16, 1024, 0, stream>>>(g_bf, w1, b1, h_bf);

  // 3) GEMM2: mega-chunk contiguous stage; w = sigmoid(h @ w2^T + b2)
  gemm2_kernel<<<512, 512, 0, stream>>>(h_bf, w2, b2, wout, feat);

  // 4) einsum -> feat (atomic accumulate over 16 c-chunks)
  einsum_kernel<<<64 * 16, 256, 0, stream>>>(x, wout, feat);
}